// Round 1
// 243.709 us; speedup vs baseline: 1.1615x; 1.1615x over previous
//
#include <hip/hip_runtime.h>

// ---------------------------------------------------------------------------
// Problem constants
//   B=16, C=512, H=W=32 -> T=1024, HEADS=8, HD=64, pairs F=32
// ---------------------------------------------------------------------------

typedef __bf16 bf16x8 __attribute__((ext_vector_type(8)));
typedef float  f32x4  __attribute__((ext_vector_type(4)));

__device__ __forceinline__ f32x4 mfma16(bf16x8 a, bf16x8 b, f32x4 c) {
    return __builtin_amdgcn_mfma_f32_16x16x32_bf16(a, b, c, 0, 0, 0);
}

// async 16B global -> LDS (dest = wave-uniform base + lane*16)
__device__ __forceinline__ void async16(const void* g, void* l) {
    __builtin_amdgcn_global_load_lds(
        (const __attribute__((address_space(1))) void*)g,
        (__attribute__((address_space(3))) void*)l, 16, 0, 0);
}

// ---------------------------------------------------------------------------
// 1) weight conversion fp32 -> bf16
// ---------------------------------------------------------------------------
__global__ void k_convert_w(const float* __restrict__ wq, const float* __restrict__ wo,
                            __bf16* __restrict__ wqb, __bf16* __restrict__ wob) {
    int i = blockIdx.x * 256 + threadIdx.x;          // grid covers 786432
    if (i < 3 * 512 * 512) wqb[i] = (__bf16)wq[i];
    if (i < 512 * 512)     wob[i] = (__bf16)wo[i];
}

// ---------------------------------------------------------------------------
// 2) x [B][C][T] fp32  ->  xt [B*T][C] bf16   (LDS tile transpose)
// ---------------------------------------------------------------------------
__global__ void k_transpose_x(const float* __restrict__ x, __bf16* __restrict__ xt) {
    __shared__ float tile[32][33];
    const int b  = blockIdx.z;
    const int c0 = blockIdx.y * 32;
    const int t0 = blockIdx.x * 32;
    const int tx = threadIdx.x, ty = threadIdx.y;    // (32, 8)
    const float* xp = x + ((size_t)b * 512 + c0) * 1024 + t0;
#pragma unroll
    for (int j = 0; j < 4; j++)
        tile[ty + j * 8][tx] = xp[(ty + j * 8) * 1024 + tx];
    __syncthreads();
    __bf16* xo = xt + ((size_t)b * 1024 + t0) * 512 + c0;
#pragma unroll
    for (int j = 0; j < 4; j++)
        xo[(ty + j * 8) * 512 + tx] = (__bf16)tile[tx][ty + j * 8];
}

// ---------------------------------------------------------------------------
// 3) QKV GEMM 16384x1536x512 + fused bias + SO(2) rotation + head split.
//    R(this): 128x128 tile (m97 structure, 32 MFMA/wave/round vs 16 at
//    128x64 -> doubles MFMA:barrier ratio; ladder-verified 874-912 TF at
//    4096^3). Head-grouped column mapping: blockIdx.y -> (part, 2 heads);
//    local col c -> W row o = part*512 + (c&63)*8 + nh_base + (c>>6).
//    => nh is wave-uniform, q/k stores are 32B-contiguous runs tiling full
//    128B destination rows (kills the 1.7x write amplification of the old
//    nh-interleaved 2B scatter), v packs 4 consecutive-t bf16 per 8B store.
//    XOR chunk swizzle unchanged (0 conflicts measured, R3).
//    Grid 128x12 = 1536 blocks, LDS 32 KB, 4 waves in 2x2.
// ---------------------------------------------------------------------------
__global__ __launch_bounds__(256) void k_gemm_qkv(
        const __bf16* __restrict__ A, const __bf16* __restrict__ W,
        const float* __restrict__ bias,
        const float* __restrict__ matq, const float* __restrict__ matk,
        const float* __restrict__ matv,
        __bf16* __restrict__ qd, __bf16* __restrict__ kd, __bf16* __restrict__ vtd)
{
    __shared__ __bf16 As[128][64];   // 16 KB
    __shared__ __bf16 Bs[128][64];   // 16 KB
    const int tid = threadIdx.x;
    const int m0 = blockIdx.x * 128;
    const int jb = blockIdx.y;              // 0..11
    const int part = jb >> 2;               // 0=q 1=k 2=v (uniform per block)
    const int nh_base = (jb & 3) * 2;       // heads {nh_base, nh_base+1}
    const int lane = tid & 63, w = tid >> 6;
    const int ln = lane & 15, quad = lane >> 4;
    const int wr = w >> 1, wc = w & 1;      // 2x2 wave grid, 64x64 each

    const int srow = lane >> 3;                       // 0..7
    const int scol = (((lane & 7) ^ srow) * 8);       // xor chunk swizzle

    // Per-lane source row pointers (hoisted out of the k-loop).
    // B LDS row rr holds W row o(rr) = part*512 + (rr&63)*8 + nh_base + (rr>>6)
    const __bf16* arow[4];
    const __bf16* brow[4];
#pragma unroll
    for (int jj = 0; jj < 4; jj++) {
        int rr = w * 32 + jj * 8 + srow;              // 0..127
        arow[jj] = &A[(size_t)(m0 + rr) * 512 + scol];
        int o = part * 512 + (rr & 63) * 8 + nh_base + (rr >> 6);
        brow[jj] = &W[(size_t)o * 512 + scol];
    }

    f32x4 acc[4][4] = {};

    for (int k0 = 0; k0 < 512; k0 += 64) {
#pragma unroll
        for (int jj = 0; jj < 4; jj++)
            async16(arow[jj] + k0, &As[w * 32 + jj * 8][0]);
#pragma unroll
        for (int jj = 0; jj < 4; jj++)
            async16(brow[jj] + k0, &Bs[w * 32 + jj * 8][0]);
        __syncthreads();
#pragma unroll
        for (int h = 0; h < 2; h++) {
            bf16x8 af[4], wf[4];
#pragma unroll
            for (int mi = 0; mi < 4; mi++)
                af[mi] = *(const bf16x8*)&As[wr * 64 + mi * 16 + ln][(((h * 4 + quad) ^ (ln & 7)) * 8)];
#pragma unroll
            for (int ni = 0; ni < 4; ni++)
                wf[ni] = *(const bf16x8*)&Bs[wc * 64 + ni * 16 + ln][(((h * 4 + quad) ^ (ln & 7)) * 8)];
#pragma unroll
            for (int mi = 0; mi < 4; mi++)
#pragma unroll
                for (int ni = 0; ni < 4; ni++)
                    acc[mi][ni] = mfma16(af[mi], wf[ni], acc[mi][ni]);
        }
        __syncthreads();
    }

    // Epilogue. Wave-uniform head: nh = nh_base + wc; hd = ni*16 + ln.
    // Rotation pair partner = hd^1 -> lane^1 (all lanes active, no divergence).
    const int nh = nh_base + wc;
    const int rowbase = m0 + wr * 64;
    const int b  = rowbase >> 10, t0 = rowbase & 1023;
    const int bh = b * 8 + nh;
    const int ip = ln & 1;
    const float2* matp = (const float2*)(part == 0 ? matq : (part == 1 ? matk : matv));
    __bf16* qkdst = (part == 0) ? qd : kd;

#pragma unroll
    for (int ni = 0; ni < 4; ni++) {
        const int hd = ni * 16 + ln;
        const int f  = hd >> 1;
        const float bias_o = bias[part * 512 + hd * 8 + nh];
#pragma unroll
        for (int mi = 0; mi < 4; mi++) {
            const int tq = t0 + mi * 16 + quad * 4;   // first of this frag's 4 t's
            if (part < 2) {
#pragma unroll
                for (int r = 0; r < 4; r++) {
                    int t = tq + r;
                    float val = acc[mi][ni][r] + bias_o;
                    float pr  = __shfl_xor(val, 1);
                    float2 mv = matp[((size_t)t * 32 + f) * 2 + ip];
                    float e  = ip ? pr : val;
                    float oo = ip ? val : pr;
                    float rv = mv.x * e + mv.y * oo;
                    qkdst[((size_t)bh * 1024 + t) * 64 + hd] = (__bf16)rv;
                }
            } else {
                __bf16 pack[4];
#pragma unroll
                for (int r = 0; r < 4; r++) {
                    int t = tq + r;
                    float val = acc[mi][ni][r] + bias_o;
                    float pr  = __shfl_xor(val, 1);
                    float2 mv = matp[((size_t)t * 32 + f) * 2 + ip];
                    float e  = ip ? pr : val;
                    float oo = ip ? val : pr;
                    pack[r] = (__bf16)(mv.x * e + mv.y * oo);
                }
                *(uint2*)&vtd[((size_t)bh * 64 + hd) * 1024 + tq] = *(const uint2*)pack;
            }
        }
    }
}

// ---------------------------------------------------------------------------
// 4) Flash attention per (qtile=128 rows, head, batch); s-tile = 64.
//    No-max softmax (scores tiny), deferred l-reduction, fused mat_o rotation.
//    (unchanged this round — no counters for it yet)
// ---------------------------------------------------------------------------
__global__ __launch_bounds__(256) void k_attn(
        const __bf16* __restrict__ q, const __bf16* __restrict__ kk,
        const __bf16* __restrict__ vt, const float* __restrict__ mato,
        __bf16* __restrict__ od)
{
    __shared__ __bf16 Ks[64][72];        // [s][d]
    __shared__ __bf16 Vs[64][72];        // [hd][s]  (V pre-transposed in global)
    __shared__ __bf16 Ps[4][32][72];     // per-wave P round-trip C-layout -> A-layout
    const int qt = blockIdx.x, nh = blockIdx.y, b = blockIdx.z;
    const int bh = b * 8 + nh;
    const int tid = threadIdx.x, w = tid >> 6, lane = tid & 63;
    const int ln = lane & 15, quad = lane >> 4;
    const int qr0 = qt * 128 + w * 32;   // this wave's 32 q-rows

    bf16x8 qa[2][2];
#pragma unroll
    for (int mi = 0; mi < 2; mi++)
#pragma unroll
        for (int ki = 0; ki < 2; ki++)
            qa[mi][ki] = *(const bf16x8*)&q[((size_t)bh * 1024 + qr0 + mi * 16 + ln) * 64 + ki * 32 + quad * 8];

    f32x4 oacc[2][4] = {};
    float lr[2][4] = {};                 // per-lane partial row sums

    const float C_EXP = 0.18033688011112042f;  // 0.125 * log2(e)

    for (int st = 0; st < 16; st++) {
        // stage K [64][64] and V^T [64][64]
#pragma unroll
        for (int c = 0; c < 2; c++) {
            int idx = tid + c * 256;                 // 512 chunks each
            int row = idx >> 3, g = (idx & 7) * 8;
            *(bf16x8*)&Ks[row][g] = *(const bf16x8*)&kk[((size_t)bh * 1024 + st * 64 + row) * 64 + g];
            *(bf16x8*)&Vs[row][g] = *(const bf16x8*)&vt[((size_t)bh * 64 + row) * 1024 + st * 64 + g];
        }
        __syncthreads();

        // S = Q K^T  (32 x 64 per wave)
        f32x4 s[2][4] = {};
#pragma unroll
        for (int si = 0; si < 4; si++) {
            bf16x8 kb0 = *(const bf16x8*)&Ks[si * 16 + ln][quad * 8];
            bf16x8 kb1 = *(const bf16x8*)&Ks[si * 16 + ln][32 + quad * 8];
#pragma unroll
            for (int mi = 0; mi < 2; mi++) {
                s[mi][si] = mfma16(qa[mi][0], kb0, s[mi][si]);
                s[mi][si] = mfma16(qa[mi][1], kb1, s[mi][si]);
            }
        }

        // p = exp2(s * C_EXP); per-lane partial sums; P -> wave-private LDS
#pragma unroll
        for (int mi = 0; mi < 2; mi++)
#pragma unroll
            for (int si = 0; si < 4; si++)
#pragma unroll
                for (int r = 0; r < 4; r++) {
                    float p = exp2f(s[mi][si][r] * C_EXP);
                    lr[mi][r] += p;
                    Ps[w][mi * 16 + quad * 4 + r][si * 16 + ln] = (__bf16)p;
                }

        // O += P V
#pragma unroll
        for (int kt = 0; kt < 2; kt++) {
            bf16x8 pa0 = *(const bf16x8*)&Ps[w][ln][kt * 32 + quad * 8];
            bf16x8 pa1 = *(const bf16x8*)&Ps[w][16 + ln][kt * 32 + quad * 8];
#pragma unroll
            for (int ni = 0; ni < 4; ni++) {
                bf16x8 vb = *(const bf16x8*)&Vs[ni * 16 + ln][kt * 32 + quad * 8];
                oacc[0][ni] = mfma16(pa0, vb, oacc[0][ni]);
                oacc[1][ni] = mfma16(pa1, vb, oacc[1][ni]);
            }
        }
        __syncthreads();
    }

    // reduce row sums across the 16 lanes holding each row
    float inv[2][4];
#pragma unroll
    for (int mi = 0; mi < 2; mi++)
#pragma unroll
        for (int r = 0; r < 4; r++) {
            float v = lr[mi][r];
#pragma unroll
            for (int d = 1; d <= 8; d <<= 1) v += __shfl_xor(v, d);
            inv[mi][r] = 1.0f / v;
        }

    // epilogue: *inv, rotate with mat_o (pair = hd^1 -> lane^1), store o_rot
    const float2* mo2 = (const float2*)mato;
#pragma unroll
    for (int mi = 0; mi < 2; mi++) {
#pragma unroll
        for (int ni = 0; ni < 4; ni++) {
            int hd = ni * 16 + ln;
            int f = hd >> 1, ip = ln & 1;
#pragma unroll
            for (int r = 0; r < 4; r++) {
                int t = qr0 + mi * 16 + quad * 4 + r;
                float val = oacc[mi][ni][r] * inv[mi][r];
                float pr  = __shfl_xor(val, 1);
                float2 mv = mo2[(t * 32 + f) * 2 + ip];
                float e  = ip ? pr : val;
                float oo = ip ? val : pr;
                float rv = mv.x * e + mv.y * oo;
                od[((size_t)b * 1024 + t) * 512 + hd * 8 + nh] = (__bf16)rv;
            }
        }
    }
}

// ---------------------------------------------------------------------------
// 5) out-proj GEMM 16384x512x512 + bias, fp32 output [b][o][t]
//    R(this): 128x128 tile, same m97-structure main loop as k_gemm_qkv
//    (32 MFMA/wave/round). Grid 128x4 = 512 blocks (2/CU, all CUs busy).
// ---------------------------------------------------------------------------
__global__ __launch_bounds__(256) void k_gemm_out(
        const __bf16* __restrict__ A, const __bf16* __restrict__ W,
        const float* __restrict__ bias, float* __restrict__ out)
{
    __shared__ __bf16 As[128][64];
    __shared__ __bf16 Bs[128][64];
    const int tid = threadIdx.x;
    const int m0 = blockIdx.x * 128;
    const int n0 = blockIdx.y * 128;
    const int lane = tid & 63, w = tid >> 6;
    const int ln = lane & 15, quad = lane >> 4;
    const int wr = w >> 1, wc = w & 1;

    const int srow = lane >> 3;
    const int scol = (((lane & 7) ^ srow) * 8);

    const __bf16* arow[4];
    const __bf16* brow[4];
#pragma unroll
    for (int jj = 0; jj < 4; jj++) {
        int rr = w * 32 + jj * 8 + srow;
        arow[jj] = &A[(size_t)(m0 + rr) * 512 + scol];
        brow[jj] = &W[(size_t)(n0 + rr) * 512 + scol];
    }

    f32x4 acc[4][4] = {};

    for (int k0 = 0; k0 < 512; k0 += 64) {
#pragma unroll
        for (int jj = 0; jj < 4; jj++)
            async16(arow[jj] + k0, &As[w * 32 + jj * 8][0]);
#pragma unroll
        for (int jj = 0; jj < 4; jj++)
            async16(brow[jj] + k0, &Bs[w * 32 + jj * 8][0]);
        __syncthreads();
#pragma unroll
        for (int h = 0; h < 2; h++) {
            bf16x8 af[4], wf[4];
#pragma unroll
            for (int mi = 0; mi < 4; mi++)
                af[mi] = *(const bf16x8*)&As[wr * 64 + mi * 16 + ln][(((h * 4 + quad) ^ (ln & 7)) * 8)];
#pragma unroll
            for (int ni = 0; ni < 4; ni++)
                wf[ni] = *(const bf16x8*)&Bs[wc * 64 + ni * 16 + ln][(((h * 4 + quad) ^ (ln & 7)) * 8)];
#pragma unroll
            for (int mi = 0; mi < 4; mi++)
#pragma unroll
                for (int ni = 0; ni < 4; ni++)
                    acc[mi][ni] = mfma16(af[mi], wf[ni], acc[mi][ni]);
        }
        __syncthreads();
    }

    const int rowbase = m0 + wr * 64;
    const int bb = rowbase >> 10, t0 = rowbase & 1023;
#pragma unroll
    for (int ni = 0; ni < 4; ni++) {
        int o = n0 + wc * 64 + ni * 16 + ln;
        float bias_o = bias[o];
#pragma unroll
        for (int mi = 0; mi < 4; mi++) {
            int t = t0 + mi * 16 + quad * 4;
            f32x4 v = acc[mi][ni];
            v[0] += bias_o; v[1] += bias_o; v[2] += bias_o; v[3] += bias_o;
            *(f32x4*)&out[((size_t)bb * 512 + o) * 1024 + t] = v;
        }
    }
}

// ---------------------------------------------------------------------------
extern "C" void kernel_launch(void* const* d_in, const int* in_sizes, int n_in,
                              void* d_out, int out_size, void* d_ws, size_t ws_size,
                              hipStream_t stream) {
    (void)in_sizes; (void)n_in; (void)out_size; (void)ws_size;
    const float* x     = (const float*)d_in[0];
    const float* w_qkv = (const float*)d_in[1];
    const float* b_qkv = (const float*)d_in[2];
    const float* w_o   = (const float*)d_in[3];
    const float* b_o   = (const float*)d_in[4];
    const float* mat_q = (const float*)d_in[5];
    const float* mat_k = (const float*)d_in[6];
    const float* mat_v = (const float*)d_in[7];
    const float* mat_o = (const float*)d_in[8];
    float* out = (float*)d_out;

    char* p = (char*)d_ws;
    __bf16* wqb = (__bf16*)p;  p += (size_t)3 * 512 * 512 * 2;        // 1.5 MB
    __bf16* wob = (__bf16*)p;  p += (size_t)512 * 512 * 2;            // 0.5 MB
    char* xt_base = p;
    __bf16* xt  = (__bf16*)p;  p += (size_t)16384 * 512 * 2;          // 16.8 MB
    __bf16* qd  = (__bf16*)p;  p += (size_t)128 * 1024 * 64 * 2;      // 16.8 MB
    __bf16* kd  = (__bf16*)p;  p += (size_t)128 * 1024 * 64 * 2;      // 16.8 MB
    __bf16* vtd = (__bf16*)p;  p += (size_t)128 * 64 * 1024 * 2;      // 16.8 MB
    __bf16* od  = (__bf16*)xt_base;   // alias: xt dead after k_gemm_qkv

    k_convert_w  <<<dim3(3072),       dim3(256),    0, stream>>>(w_qkv, w_o, wqb, wob);
    k_transpose_x<<<dim3(32, 16, 16), dim3(32, 8),  0, stream>>>(x, xt);
    k_gemm_qkv   <<<dim3(128, 12),    dim3(256),    0, stream>>>(xt, wqb, b_qkv, mat_q, mat_k, mat_v, qd, kd, vtd);
    k_attn       <<<dim3(8, 8, 16),   dim3(256),    0, stream>>>(qd, kd, vtd, mat_o, od);
    k_gemm_out   <<<dim3(128, 4),     dim3(256),    0, stream>>>(od, wob, b_o, out);
}